// Round 1
// baseline (668.073 us; speedup 1.0000x reference)
//
#include <hip/hip_runtime.h>
#include <stdint.h>
#include <stddef.h>

#define NTOK 8192
#define DDIM 1024
#define NEXP 8
#define HDIM 2048
#define MAXROWS (2 * NTOK + NEXP * 128) /* 17408 compacted+padded expert rows */

typedef __attribute__((ext_vector_type(4))) float f32x4;
typedef __attribute__((ext_vector_type(8))) short s16x8;

static __device__ __forceinline__ unsigned short f2bf(float f) {
  union { float f; unsigned u; } v; v.f = f;
  unsigned r = v.u + 0x7FFFu + ((v.u >> 16) & 1u); // RNE
  return (unsigned short)(r >> 16);
}

static __device__ __forceinline__ void gll16(const void* g, void* l) {
  __builtin_amdgcn_global_load_lds((const __attribute__((address_space(1))) void*)g,
                                   (__attribute__((address_space(3))) void*)l, 16, 0, 0);
}

__global__ void k_sentinel(float* out) { if (threadIdx.x == 0) out[0] = 1.0e6f; }

// ---- fp32 -> bf16 bulk convert; n8 = count/8 ----
__global__ __launch_bounds__(256) void k_cvt(const float* __restrict__ src,
                                             unsigned short* __restrict__ dst, int n8) {
  int i = blockIdx.x * blockDim.x + threadIdx.x;
  int stride = gridDim.x * blockDim.x;
  for (; i < n8; i += stride) {
    const f32x4* s = (const f32x4*)(src + (size_t)i * 8);
    f32x4 a = s[0], b = s[1];
    s16x8 o;
    o[0] = f2bf(a[0]); o[1] = f2bf(a[1]); o[2] = f2bf(a[2]); o[3] = f2bf(a[3]);
    o[4] = f2bf(b[0]); o[5] = f2bf(b[1]); o[6] = f2bf(b[2]); o[7] = f2bf(b[3]);
    *(s16x8*)(dst + (size_t)i * 8) = o;
  }
}

// ---- router: fp32 logits, top-2 (lower-index tie-break), softmax, list append ----
__global__ __launch_bounds__(256) void k_router(const float* __restrict__ x,
    const float* __restrict__ gw, int* __restrict__ cnt,
    int* __restrict__ listTok, float* __restrict__ listW) {
  int lane = threadIdx.x & 63;
  int t = blockIdx.x * 4 + (threadIdx.x >> 6);
  const f32x4* x4 = (const f32x4*)x;
  const f32x4* g4 = (const f32x4*)gw;
  f32x4 xr[4];
#pragma unroll
  for (int j = 0; j < 4; ++j) xr[j] = x4[(size_t)t * 256 + j * 64 + lane];
  float le[8];
#pragma unroll
  for (int e = 0; e < 8; ++e) {
    float p = 0.f;
#pragma unroll
    for (int j = 0; j < 4; ++j) {
      f32x4 g = g4[e * 256 + j * 64 + lane];
      p += xr[j][0] * g[0] + xr[j][1] * g[1] + xr[j][2] * g[2] + xr[j][3] * g[3];
    }
#pragma unroll
    for (int off = 32; off > 0; off >>= 1) p += __shfl_xor(p, off, 64);
    le[e] = p;
  }
  if (lane == 0) {
    int i0 = 0; float v0 = le[0];
#pragma unroll
    for (int e = 1; e < 8; ++e) if (le[e] > v0) { v0 = le[e]; i0 = e; }
    int i1 = -1; float v1 = 0.f;
#pragma unroll
    for (int e = 0; e < 8; ++e) if (e != i0 && (i1 < 0 || le[e] > v1)) { v1 = le[e]; i1 = e; }
    float b = __expf(v1 - v0);
    float s = 1.f + b;
    int p0 = atomicAdd(&cnt[i0], 1);
    listTok[i0 * NTOK + p0] = t; listW[i0 * NTOK + p0] = 1.f / s;
    int p1 = atomicAdd(&cnt[i1], 1);
    listTok[i1 * NTOK + p1] = t; listW[i1 * NTOK + p1] = b / s;
  }
}

// ---- rowbase prefix (counts rounded up to 128) ----
__global__ void k_prefix(int* ctrl) {
  if (threadIdx.x == 0) {
    int acc = 0;
#pragma unroll
    for (int e = 0; e < NEXP; ++e) { ctrl[8 + e] = acc; acc += (ctrl[e] + 127) & ~127; }
  }
}

// ---- GEMM1: h = silu(Xg @ Wg^T) * (Xg @ Wi^T), gathered rows, bf16 out ----
// tile 128(M) x 64(Ncols of H) x BK=32; 4 waves in 2x2; dual accumulators
__global__ __launch_bounds__(256) void k_gemm1(const unsigned short* __restrict__ xbf,
    const unsigned short* __restrict__ wg, const unsigned short* __restrict__ wi,
    const int* __restrict__ ctrl, const int* __restrict__ listTok,
    unsigned short* __restrict__ hbuf) {
  int e = blockIdx.z;
  int cnt = ctrl[e];
  int m0 = blockIdx.y * 128;
  if (m0 >= cnt) return;
  int rowb = ctrl[8 + e];
  int n0 = blockIdx.x * 64;

  __shared__ unsigned short lA[128 * 32];
  __shared__ unsigned short lBg[64 * 32];
  __shared__ unsigned short lBi[64 * 32];

  int tid = threadIdx.x, lane = tid & 63;
  int wv = tid >> 6, wr = wv >> 1, wc = wv & 1;
  int row4 = tid >> 2, c8 = (tid & 3) * 8;

  int tokA0 = listTok[e * NTOK + m0 + row4];        // pad rows read 0 (zero-init list)
  int tokA1 = listTok[e * NTOK + m0 + 64 + row4];
  const unsigned short* srcA0 = xbf + (size_t)tokA0 * DDIM + c8;
  const unsigned short* srcA1 = xbf + (size_t)tokA1 * DDIM + c8;
  const unsigned short* srcBg = wg + ((size_t)e * HDIM + n0 + row4) * DDIM + c8;
  const unsigned short* srcBi = wi + ((size_t)e * HDIM + n0 + row4) * DDIM + c8;

  char* ldsA = (char*)lA + (wv << 10);
  char* ldsBg = (char*)lBg + (wv << 10);
  char* ldsBi = (char*)lBi + (wv << 10);

  int aoff[4], boff[2];
#pragma unroll
  for (int f = 0; f < 4; ++f) aoff[f] = (wr * 64 + f * 16 + (lane & 15)) * 32 + (lane >> 4) * 8;
#pragma unroll
  for (int f = 0; f < 2; ++f) boff[f] = (wc * 32 + f * 16 + (lane & 15)) * 32 + (lane >> 4) * 8;

  f32x4 accg[4][2], acci[4][2];
#pragma unroll
  for (int i = 0; i < 4; ++i)
#pragma unroll
    for (int j = 0; j < 2; ++j) {
      accg[i][j] = (f32x4){0.f, 0.f, 0.f, 0.f};
      acci[i][j] = (f32x4){0.f, 0.f, 0.f, 0.f};
    }

  for (int k0 = 0; k0 < DDIM; k0 += 32) {
    gll16(srcA0 + k0, ldsA);
    gll16(srcA1 + k0, ldsA + 4096);
    gll16(srcBg + k0, ldsBg);
    gll16(srcBi + k0, ldsBi);
    __syncthreads();   // compiler drains vmcnt before barrier -> LDS tile ready
    s16x8 a[4], bg[2], bi[2];
#pragma unroll
    for (int f = 0; f < 4; ++f) a[f] = *(const s16x8*)&lA[aoff[f]];
#pragma unroll
    for (int f = 0; f < 2; ++f) { bg[f] = *(const s16x8*)&lBg[boff[f]]; bi[f] = *(const s16x8*)&lBi[boff[f]]; }
#pragma unroll
    for (int fm = 0; fm < 4; ++fm)
#pragma unroll
      for (int fn = 0; fn < 2; ++fn) {
        accg[fm][fn] = __builtin_amdgcn_mfma_f32_16x16x32_bf16(a[fm], bg[fn], accg[fm][fn], 0, 0, 0);
        acci[fm][fn] = __builtin_amdgcn_mfma_f32_16x16x32_bf16(a[fm], bi[fn], acci[fm][fn], 0, 0, 0);
      }
    __syncthreads();   // all waves done reading before next stage overwrites
  }

#pragma unroll
  for (int fm = 0; fm < 4; ++fm)
#pragma unroll
    for (int fn = 0; fn < 2; ++fn)
#pragma unroll
      for (int j = 0; j < 4; ++j) {
        int r = wr * 64 + fm * 16 + ((lane >> 4) << 2) + j;   // C/D: row=(lane>>4)*4+j
        int cc = wc * 32 + fn * 16 + (lane & 15);             //      col=lane&15
        float g = accg[fm][fn][j];
        float iv = acci[fm][fn][j];
        float hv = g / (1.f + __expf(-g)) * iv;               // silu(g)*i in fp32
        hbuf[(size_t)(rowb + m0 + r) * HDIM + n0 + cc] = f2bf(hv);
      }
}

// ---- GEMM2: out[token] += w * (h @ Wo^T); tile 128x128xBK=32 ----
__global__ __launch_bounds__(256) void k_gemm2(const unsigned short* __restrict__ hbuf,
    const unsigned short* __restrict__ wo, const int* __restrict__ ctrl,
    const int* __restrict__ listTok, const float* __restrict__ listW,
    float* __restrict__ out) {
  int e = blockIdx.z;
  int cnt = ctrl[e];
  int m0 = blockIdx.y * 128;
  if (m0 >= cnt) return;
  int rowb = ctrl[8 + e];
  int n0 = blockIdx.x * 128;

  __shared__ unsigned short lA[128 * 32];
  __shared__ unsigned short lB[128 * 32];

  int tid = threadIdx.x, lane = tid & 63;
  int wv = tid >> 6, wr = wv >> 1, wc = wv & 1;
  int row4 = tid >> 2, c8 = (tid & 3) * 8;

  const unsigned short* srcA0 = hbuf + (size_t)(rowb + m0 + row4) * HDIM + c8;
  const unsigned short* srcA1 = hbuf + (size_t)(rowb + m0 + 64 + row4) * HDIM + c8;
  const unsigned short* srcB0 = wo + ((size_t)e * DDIM + n0 + row4) * HDIM + c8;
  const unsigned short* srcB1 = wo + ((size_t)e * DDIM + n0 + 64 + row4) * HDIM + c8;

  char* ldsA = (char*)lA + (wv << 10);
  char* ldsB = (char*)lB + (wv << 10);

  int aoff[4], boff[4];
#pragma unroll
  for (int f = 0; f < 4; ++f) {
    aoff[f] = (wr * 64 + f * 16 + (lane & 15)) * 32 + (lane >> 4) * 8;
    boff[f] = (wc * 64 + f * 16 + (lane & 15)) * 32 + (lane >> 4) * 8;
  }

  f32x4 acc[4][4];
#pragma unroll
  for (int i = 0; i < 4; ++i)
#pragma unroll
    for (int j = 0; j < 4; ++j) acc[i][j] = (f32x4){0.f, 0.f, 0.f, 0.f};

  for (int k0 = 0; k0 < HDIM; k0 += 32) {
    gll16(srcA0 + k0, ldsA);
    gll16(srcA1 + k0, ldsA + 4096);
    gll16(srcB0 + k0, ldsB);
    gll16(srcB1 + k0, ldsB + 4096);
    __syncthreads();
    s16x8 a[4], b[4];
#pragma unroll
    for (int f = 0; f < 4; ++f) { a[f] = *(const s16x8*)&lA[aoff[f]]; b[f] = *(const s16x8*)&lB[boff[f]]; }
#pragma unroll
    for (int fm = 0; fm < 4; ++fm)
#pragma unroll
      for (int fn = 0; fn < 4; ++fn)
        acc[fm][fn] = __builtin_amdgcn_mfma_f32_16x16x32_bf16(a[fm], b[fn], acc[fm][fn], 0, 0, 0);
    __syncthreads();
  }

#pragma unroll
  for (int fm = 0; fm < 4; ++fm)
#pragma unroll
    for (int j = 0; j < 4; ++j) {
      int r = wr * 64 + fm * 16 + ((lane >> 4) << 2) + j;
      int mrow = m0 + r;
      if (mrow < cnt) {
        int tok = listTok[e * NTOK + mrow];
        float wgt = listW[e * NTOK + mrow];
#pragma unroll
        for (int fn = 0; fn < 4; ++fn) {
          int cc = n0 + wc * 64 + fn * 16 + (lane & 15);
          atomicAdd(&out[(size_t)tok * DDIM + cc], acc[fm][fn][j] * wgt);
        }
      }
    }
}

extern "C" void kernel_launch(void* const* d_in, const int* in_sizes, int n_in,
                              void* d_out, int out_size, void* d_ws, size_t ws_size,
                              hipStream_t stream) {
  const float* x     = (const float*)d_in[0];
  const float* gw    = (const float*)d_in[1];
  const float* wgate = (const float*)d_in[2];
  const float* win   = (const float*)d_in[3];
  const float* wout  = (const float*)d_in[4];
  float* out = (float*)d_out;

  const size_t OFF_LIST   = 256;
  const size_t OFF_LISTW  = OFF_LIST + (size_t)NEXP * NTOK * 4;
  const size_t CTRL_BYTES = OFF_LISTW + (size_t)NEXP * NTOK * 4;
  const size_t OFF_XBF = (size_t)1 << 20;
  const size_t OFF_WG  = OFF_XBF + (size_t)NTOK * DDIM * 2;
  const size_t OFF_WI  = OFF_WG + (size_t)NEXP * HDIM * DDIM * 2;
  const size_t OFF_WO  = OFF_WI + (size_t)NEXP * HDIM * DDIM * 2;
  const size_t OFF_H   = OFF_WO + (size_t)NEXP * DDIM * HDIM * 2;
  const size_t TOTAL   = OFF_H + (size_t)MAXROWS * HDIM * 2;

  if (ws_size < TOTAL) { k_sentinel<<<1, 64, 0, stream>>>(out); return; }

  char* ws = (char*)d_ws;
  int* ctrl            = (int*)ws;                       // [0..7]=cnt, [8..15]=rowbase
  int* listTok         = (int*)(ws + OFF_LIST);
  float* listW         = (float*)(ws + OFF_LISTW);
  unsigned short* xbf  = (unsigned short*)(ws + OFF_XBF);
  unsigned short* wgb  = (unsigned short*)(ws + OFF_WG);
  unsigned short* wib  = (unsigned short*)(ws + OFF_WI);
  unsigned short* wob  = (unsigned short*)(ws + OFF_WO);
  unsigned short* hbuf = (unsigned short*)(ws + OFF_H);

  hipMemsetAsync(ws, 0, CTRL_BYTES, stream);                           // counts + token lists
  hipMemsetAsync(d_out, 0, (size_t)out_size * sizeof(float), stream);  // scatter target

  k_cvt<<<2048, 256, 0, stream>>>(x,     xbf, NTOK * DDIM / 8);
  k_cvt<<<2048, 256, 0, stream>>>(wgate, wgb, NEXP * HDIM * DDIM / 8);
  k_cvt<<<2048, 256, 0, stream>>>(win,   wib, NEXP * HDIM * DDIM / 8);
  k_cvt<<<2048, 256, 0, stream>>>(wout,  wob, NEXP * DDIM * HDIM / 8);

  k_router<<<NTOK / 4, 256, 0, stream>>>(x, gw, ctrl, listTok, listW);
  k_prefix<<<1, 64, 0, stream>>>(ctrl);

  k_gemm1<<<dim3(HDIM / 64, NTOK / 128, NEXP), 256, 0, stream>>>(xbf, wgb, wib, ctrl, listTok, hbuf);
  k_gemm2<<<dim3(DDIM / 128, NTOK / 128, NEXP), 256, 0, stream>>>(hbuf, wob, ctrl, listTok, listW, out);
}